// Round 1
// baseline (515.995 us; speedup 1.0000x reference)
//
#include <hip/hip_runtime.h>
#include <stdint.h>

// ---------------------------------------------------------------------------
// KnowledgeCircuit: B=4 S=2048 D=1024 N=64 R=128, M = B*S = 8192 tokens.
// Round 6: GEMM1 -> 256x256 8-phase counted-vmcnt schedule (T2+T3+T4+T5).
//   GEMM1: y[m, n*128+r] = sum_d x[m,d] F[n,d,r]   (kc_gemm256, bf16 out)
//   mid  : h[m,r] = sum_n w1[m,n] y[m,n*128+r];  y <- g[m,nr] = w2[m,n]h[m,r]
//   GEMM2: out = g @ Rk_flat                       (kc_gemm 128^2, fp32 out)
// Schedule ledger (verified on paper): per K-tile T, 4 quadrant phases
// (ih,jh) = (0,0),(0,1),(1,0),(1,1). Each wave reads ONE A-half (wm) and
// ONE B-half (wn). Region last-reads: A-ih0 @p2, B-jh0 @p3, rest @p4.
// Issues: p1 -> T+1 second halves (4 loads, buf^1, freed @T-1.p4);
//         p3 -> T+2 A-first (2 loads, buf, freed @p2);
//         p4 -> T+2 B-first (2 loads, buf, freed @p3).
// vmcnt(4) once per K-tile at p4-end clears everything except p3+p4's 4
// loads => all of tile T+1 resident before T+1.p1. Last two tiles: vmcnt(0).
// Raw s_barrier everywhere (NO __syncthreads -> no vmcnt(0) drain).
// ---------------------------------------------------------------------------

typedef unsigned short ushort_t;
typedef __attribute__((ext_vector_type(8))) short frag_t;   // 8 bf16
typedef __attribute__((ext_vector_type(4))) float f32x4;

#define BK 64

__device__ __forceinline__ unsigned short f2bf(float f) {
    unsigned int u = __builtin_bit_cast(unsigned int, f);
    u = (u + 0x7FFFu + ((u >> 16) & 1u)) >> 16;   // RTNE
    return (unsigned short)u;
}
__device__ __forceinline__ float bf2f_lo(unsigned int v) {
    return __builtin_bit_cast(float, v << 16);
}
__device__ __forceinline__ float bf2f_hi(unsigned int v) {
    return __builtin_bit_cast(float, v & 0xFFFF0000u);
}

__device__ __forceinline__ void glds16(const ushort_t* g, ushort_t* l) {
    __builtin_amdgcn_global_load_lds(
        (const __attribute__((address_space(1))) unsigned int*)g,
        (__attribute__((address_space(3))) unsigned int*)l,
        16, 0, 0);
}

// ---------------- prepass: fp32 -> bf16 elementwise -------------------------
__global__ __launch_bounds__(256) void convert_bf(const float* __restrict__ in,
                                                  ushort_t* __restrict__ out, int n8) {
    int idx = blockIdx.x * 256 + threadIdx.x;
    if (idx >= n8) return;
    const float4 v0 = ((const float4*)in)[idx * 2];
    const float4 v1 = ((const float4*)in)[idx * 2 + 1];
    unsigned short b[8] = { f2bf(v0.x), f2bf(v0.y), f2bf(v0.z), f2bf(v0.w),
                            f2bf(v1.x), f2bf(v1.y), f2bf(v1.z), f2bf(v1.w) };
    ((uint4*)out)[idx] = *(const uint4*)b;
}

// ---------------- prepass: fp32 RxC -> bf16 CxR transpose (batched) ---------
__global__ __launch_bounds__(256) void transpose_bf(const float* __restrict__ in,
                                                    ushort_t* __restrict__ out,
                                                    int R, int C,
                                                    long in_bstride, long out_bstride) {
    __shared__ float tile[64][65];
    in  += (long)blockIdx.z * in_bstride;
    out += (long)blockIdx.z * out_bstride;
    const int t  = threadIdx.x;
    const int r0 = blockIdx.x * 64;
    const int c0 = blockIdx.y * 64;
    const int ci = t & 63;
    const int rb = t >> 6;
    #pragma unroll
    for (int p = 0; p < 16; ++p)
        tile[rb + 4 * p][ci] = in[(size_t)(r0 + rb + 4 * p) * C + c0 + ci];
    __syncthreads();
    const int cw = t >> 2;
    const int rg = (t & 3) * 16;
    unsigned short buf[16];
    #pragma unroll
    for (int k = 0; k < 16; ++k)
        buf[k] = f2bf(tile[rg + k][cw]);
    uint4* dst = (uint4*)&out[(size_t)(c0 + cw) * R + r0 + rg];
    dst[0] = *(const uint4*)&buf[0];
    dst[1] = *(const uint4*)&buf[8];
}

// ---------------- mid: h = w1-reduce(y); y <- g = w2 (x) h (in place) -------
__global__ __launch_bounds__(256) void mid_fuse(ushort_t* __restrict__ y,
                                                const float* __restrict__ w1,
                                                const float* __restrict__ w2) {
    const int m    = blockIdx.x * 4 + (threadIdx.x >> 6);
    const int lane = threadIdx.x & 63;
    unsigned int* yrow = (unsigned int*)(y + (size_t)m * 8192);
    const float* w1r = w1 + (size_t)m * 64;
    const float* w2r = w2 + (size_t)m * 64;
    float h0 = 0.f, h1 = 0.f;
    #pragma unroll 16
    for (int n = 0; n < 64; ++n) {
        const unsigned int v = yrow[n * 64 + lane];
        const float w = w1r[n];
        h0 += w * bf2f_lo(v);
        h1 += w * bf2f_hi(v);
    }
    #pragma unroll 16
    for (int n = 0; n < 64; ++n) {
        const float w = w2r[n];
        yrow[n * 64 + lane] =
            (unsigned int)f2bf(w * h0) | ((unsigned int)f2bf(w * h1) << 16);
    }
}

// ---------------- 256x256 8-phase GEMM (T2+T3+T4+T5) ------------------------
// C[m,n] = sum_k Ab[m,k] * Bt[n,k]; 512 threads, 8 waves (2M x 4N),
// per-wave 128x64 output, BK=64, 128 KiB LDS double buffer.
template<bool OUT_BF16>
__global__ __launch_bounds__(512, 2)
void kc_gemm256(const ushort_t* __restrict__ Ab, const ushort_t* __restrict__ Bt,
                void* __restrict__ Cout, int ldA, int ldB, int ldC, int ksteps)
{
    __shared__ ushort_t As[2][256 * BK];   // 2 x 32 KiB
    __shared__ ushort_t Bs[2][256 * BK];   // 2 x 32 KiB

    const int t    = threadIdx.x;
    const int lane = t & 63;
    const int wv   = t >> 6;
    const int m0   = blockIdx.x * 256;
    const int n0   = blockIdx.y * 256;

    const int wm = (wv >> 2) * 128;    // wave M-half: rows [wm, wm+128)
    const int wn = (wv & 3) * 64;      // wave N-quarter: cols [wn, wn+64)
    const int fr = lane & 15;
    const int q  = lane >> 4;
    const int e  = fr & 7;
    const int lrow = lane >> 3;        // staging: row within 8-row wave chunk
    const int lchk = lane & 7;         // staging: 16B chunk within row

    f32x4 acc[8][4];
    #pragma unroll
    for (int i = 0; i < 8; ++i)
        #pragma unroll
        for (int j = 0; j < 4; ++j)
            acc[i][j] = (f32x4){0.f, 0.f, 0.f, 0.f};

// One load batch = 512 threads x 16B = 64 rows. Source k-chunk is
// XOR-pre-swizzled (chunk ^ (row&7)) so linear LDS holds swizzled data;
// ds_read applies the same involution -> conflict-free (proven in 128^2).
#define ISSUE_A(abuf, ih, piece, kt) do {                                     \
        const int r0_ = (piece) * 128 + (ih) * 64 + wv * 8;                   \
        const int rr_ = r0_ + lrow;                                           \
        glds16(Ab + (size_t)(m0 + rr_) * ldA + (kt) + ((lchk ^ (rr_ & 7)) << 3), \
               &As[abuf][r0_ * BK]);                                          \
    } while (0)
// B jh-half lives in four 32-row stripes: rows piece*128 + jh*32 + {0..31}
// and +64; wave base = piece*128 + jh*32 + wv*8 + (wv>>2)*32 covers exactly
// the union of per-wave jh read ranges [wn+jh*32, wn+jh*32+32).
#define ISSUE_B(bbuf, jh, piece, kt) do {                                     \
        const int r0_ = (piece) * 128 + (jh) * 32 + wv * 8 + (wv >> 2) * 32;  \
        const int rr_ = r0_ + lrow;                                           \
        glds16(Bt + (size_t)(n0 + rr_) * ldB + (kt) + ((lchk ^ (rr_ & 7)) << 3), \
               &Bs[bbuf][r0_ * BK]);                                          \
    } while (0)
#define BAR() do { __builtin_amdgcn_s_barrier();                              \
                   __builtin_amdgcn_sched_barrier(0); } while (0)
#define VMCNT(n) do { asm volatile("s_waitcnt vmcnt(" #n ")" ::: "memory");   \
                      __builtin_amdgcn_sched_barrier(0); } while (0)
// Quadrant phase: 12 ds_read_b128 + 16 MFMA. lgkmcnt is compiler-managed
// (plain LDS loads -> fine-grained waits; all reads retired before the
// end-of-phase barrier because every read feeds an MFMA in this phase).
#define PHASE(pbuf, ih, jh) do {                                              \
        frag_t a_[2][4], b_[2][2];                                            \
        _Pragma("unroll")                                                     \
        for (int kk = 0; kk < 2; ++kk) {                                      \
            const int cs_ = ((kk * 4 + q) ^ e) * 8;                           \
            _Pragma("unroll")                                                 \
            for (int ii = 0; ii < 4; ++ii)                                    \
                a_[kk][ii] = *(const frag_t*)&As[pbuf][                       \
                    (wm + ((ih) * 4 + ii) * 16 + fr) * BK + cs_];             \
            _Pragma("unroll")                                                 \
            for (int jj = 0; jj < 2; ++jj)                                    \
                b_[kk][jj] = *(const frag_t*)&Bs[pbuf][                       \
                    (wn + ((jh) * 2 + jj) * 16 + fr) * BK + cs_];             \
        }                                                                     \
        __builtin_amdgcn_s_setprio(1);                                        \
        _Pragma("unroll")                                                     \
        for (int kk = 0; kk < 2; ++kk)                                        \
            _Pragma("unroll")                                                 \
            for (int ii = 0; ii < 4; ++ii)                                    \
                _Pragma("unroll")                                             \
                for (int jj = 0; jj < 2; ++jj)                                \
                    acc[(ih) * 4 + ii][(jh) * 2 + jj] =                       \
                        __builtin_amdgcn_mfma_f32_16x16x32_bf16(              \
                            a_[kk][ii], b_[kk][jj],                           \
                            acc[(ih) * 4 + ii][(jh) * 2 + jj], 0, 0, 0);      \
        __builtin_amdgcn_s_setprio(0);                                        \
    } while (0)

    // prologue: all of tile 0 (8 loads) + tile 1 first halves (4 loads).
    // vmcnt(4) -> tile 0 resident; tile1 A-ih0/B-jh0 may stay in flight
    // (exactly the steady-state invariant at a p1 entry).
    ISSUE_A(0, 0, 0, 0); ISSUE_A(0, 0, 1, 0);
    ISSUE_A(0, 1, 0, 0); ISSUE_A(0, 1, 1, 0);
    ISSUE_B(0, 0, 0, 0); ISSUE_B(0, 0, 1, 0);
    ISSUE_B(0, 1, 0, 0); ISSUE_B(0, 1, 1, 0);
    if (ksteps > 1) {
        ISSUE_A(1, 0, 0, BK); ISSUE_A(1, 0, 1, BK);
        ISSUE_B(1, 0, 0, BK); ISSUE_B(1, 0, 1, BK);
        VMCNT(4);
    } else {
        VMCNT(0);
    }
    BAR();

    for (int T = 0; T < ksteps; ++T) {
        const int buf = T & 1;
        const int kn1 = (T + 1) * BK;
        const int kn2 = (T + 2) * BK;
        // p1: (ih0,jh0). Issue tile T+1 second halves into buf^1
        //     (regions last read at T-1.p4; barrier crossed).
        if (T + 1 < ksteps) {
            ISSUE_A(buf ^ 1, 1, 0, kn1); ISSUE_A(buf ^ 1, 1, 1, kn1);
            ISSUE_B(buf ^ 1, 1, 0, kn1); ISSUE_B(buf ^ 1, 1, 1, kn1);
        }
        PHASE(buf, 0, 0);
        BAR();
        // p2: (ih0,jh1). Last read of A-ih0 regions.
        PHASE(buf, 0, 1);
        BAR();
        // p3: (ih1,jh0). A-ih0 of buf free -> issue T+2 A first half.
        if (T + 2 < ksteps) { ISSUE_A(buf, 0, 0, kn2); ISSUE_A(buf, 0, 1, kn2); }
        PHASE(buf, 1, 0);
        BAR();
        // p4: (ih1,jh1). B-jh0 of buf free -> issue T+2 B first half.
        if (T + 2 < ksteps) { ISSUE_B(buf, 0, 0, kn2); ISSUE_B(buf, 0, 1, kn2); }
        PHASE(buf, 1, 1);
        // counted wait: keep p3+p4's 4 loads in flight; clears tile T+1.
        if (T < ksteps - 2) { VMCNT(4); } else { VMCNT(0); }
        BAR();
    }

    // epilogue: C/D layout col=lane&15, row=q*4+reg
    #pragma unroll
    for (int i = 0; i < 8; ++i) {
        #pragma unroll
        for (int r = 0; r < 4; ++r) {
            const int gm = m0 + wm + 16 * i + q * 4 + r;
            #pragma unroll
            for (int j = 0; j < 4; ++j) {
                const int gn = n0 + wn + 16 * j + fr;
                if constexpr (OUT_BF16)
                    ((ushort_t*)Cout)[(size_t)gm * ldC + gn] = f2bf(acc[i][j][r]);
                else
                    ((float*)Cout)[(size_t)gm * ldC + gn] = acc[i][j][r];
            }
        }
    }
#undef ISSUE_A
#undef ISSUE_B
#undef BAR
#undef VMCNT
#undef PHASE
}

// ---------------- pure GEMM (128x128, round-5 known-good) -------------------
template<bool OUT_BF16>
__global__ __launch_bounds__(256, 3)
void kc_gemm(const ushort_t* __restrict__ Ab, const ushort_t* __restrict__ Bt,
             void* __restrict__ Cout, int ldA, int ldB, int ldC, int ksteps)
{
    __shared__ ushort_t As[128 * BK];
    __shared__ ushort_t Bs[128 * BK];

    const int t    = threadIdx.x;
    const int lane = t & 63;
    const int wv   = t >> 6;
    const int m0   = blockIdx.x * 128;
    const int n0   = blockIdx.y * 128;

    const int wm = (wv & 1) * 64;
    const int wn = (wv >> 1) * 64;
    const int fr = lane & 15;
    const int q  = lane >> 4;
    const int e  = fr & 7;

    int srow[4], scol[4];
    #pragma unroll
    for (int c = 0; c < 4; ++c) {
        const int s = (wv * 4 + c) * 64 + lane;
        srow[c] = s >> 3;
        scol[c] = ((s & 7) ^ (srow[c] & 7)) * 8;
    }

    f32x4 acc[4][4];
    #pragma unroll
    for (int i = 0; i < 4; ++i)
        #pragma unroll
        for (int j = 0; j < 4; ++j)
            acc[i][j] = (f32x4){0.f, 0.f, 0.f, 0.f};

    for (int ss = 0; ss < ksteps; ++ss) {
        const int k0 = ss * BK;

        __syncthreads();
        #pragma unroll
        for (int c = 0; c < 4; ++c)
            glds16(Ab + (size_t)(m0 + srow[c]) * ldA + k0 + scol[c],
                   &As[(wv * 4 + c) * 512]);
        #pragma unroll
        for (int c = 0; c < 4; ++c)
            glds16(Bt + (size_t)(n0 + srow[c]) * ldB + k0 + scol[c],
                   &Bs[(wv * 4 + c) * 512]);
        __syncthreads();

        #pragma unroll
        for (int kk = 0; kk < 2; ++kk) {
            const int csw = (kk * 4 + q) ^ e;
            frag_t a[4], b[4];
            #pragma unroll
            for (int i = 0; i < 4; ++i)
                a[i] = *(const frag_t*)&As[((wm + 16 * i + fr) * 8 + csw) * 8];
            #pragma unroll
            for (int j = 0; j < 4; ++j)
                b[j] = *(const frag_t*)&Bs[((wn + 16 * j + fr) * 8 + csw) * 8];
            #pragma unroll
            for (int i = 0; i < 4; ++i)
                #pragma unroll
                for (int j = 0; j < 4; ++j)
                    acc[i][j] = __builtin_amdgcn_mfma_f32_16x16x32_bf16(
                                    a[i], b[j], acc[i][j], 0, 0, 0);
        }
    }

    #pragma unroll
    for (int i = 0; i < 4; ++i) {
        #pragma unroll
        for (int r = 0; r < 4; ++r) {
            const int gm = m0 + wm + 16 * i + q * 4 + r;
            #pragma unroll
            for (int j = 0; j < 4; ++j) {
                const int gn = n0 + wn + 16 * j + fr;
                if constexpr (OUT_BF16)
                    ((ushort_t*)Cout)[(size_t)gm * ldC + gn] = f2bf(acc[i][j][r]);
                else
                    ((float*)Cout)[(size_t)gm * ldC + gn] = acc[i][j][r];
            }
        }
    }
}

// ---------------- fallback fold-GEMM (round-3, known-good) ------------------
template<int SHIFT, int SEG_STEPS, bool ATOMIC>
__global__ __launch_bounds__(256, 4)
void kc_gemm_fold(const ushort_t* __restrict__ Ab, const float* __restrict__ W,
                  const ushort_t* __restrict__ Bt, float* __restrict__ C,
                  int ldA, int ldB, int ldC, int ksteps)
{
    __shared__ ushort_t As[64 * BK];
    __shared__ ushort_t Bs[128 * BK];
    const int t = threadIdx.x, lane = t & 63, wv = t >> 6;
    const int m0 = blockIdx.x * 64, n0 = blockIdx.y * 128;
    const int kbase = blockIdx.z * ksteps * BK;
    const int wm = (wv & 1) * 32, wn = (wv >> 1) * 64;
    const int fr = lane & 15, q = lane >> 4, e = fr & 7;
    int arow[2], acol[2], brow[4], bcol[4];
    #pragma unroll
    for (int c = 0; c < 2; ++c) {
        const int s = (wv * 2 + c) * 64 + lane;
        arow[c] = s >> 3; acol[c] = ((s & 7) ^ (arow[c] & 7)) * 8;
    }
    #pragma unroll
    for (int c = 0; c < 4; ++c) {
        const int s = (wv * 4 + c) * 64 + lane;
        brow[c] = s >> 3; bcol[c] = ((s & 7) ^ (brow[c] & 7)) * 8;
    }
    f32x4 acc_out[2][4];
    #pragma unroll
    for (int i = 0; i < 2; ++i)
        #pragma unroll
        for (int j = 0; j < 4; ++j) acc_out[i][j] = (f32x4){0.f,0.f,0.f,0.f};
    const int nsegs = ksteps / SEG_STEPS;
    for (int seg = 0; seg < nsegs; ++seg) {
        const int segk = kbase + seg * SEG_STEPS * BK;
        const int nidx = segk >> SHIFT;
        f32x4 acc_in[2][4];
        #pragma unroll
        for (int i = 0; i < 2; ++i)
            #pragma unroll
            for (int j = 0; j < 4; ++j) acc_in[i][j] = (f32x4){0.f,0.f,0.f,0.f};
        for (int ss = 0; ss < SEG_STEPS; ++ss) {
            const int k0 = segk + ss * BK;
            const int d0 = k0 & ((1 << SHIFT) - 1);
            __syncthreads();
            #pragma unroll
            for (int c = 0; c < 2; ++c)
                glds16(Ab + (size_t)(m0 + arow[c]) * ldA + d0 + acol[c],
                       &As[(wv * 2 + c) * 512]);
            #pragma unroll
            for (int c = 0; c < 4; ++c)
                glds16(Bt + (size_t)(n0 + brow[c]) * ldB + k0 + bcol[c],
                       &Bs[(wv * 4 + c) * 512]);
            __syncthreads();
            #pragma unroll
            for (int kk = 0; kk < 2; ++kk) {
                const int csw = (kk * 4 + q) ^ e;
                frag_t a[2], b[4];
                #pragma unroll
                for (int i = 0; i < 2; ++i)
                    a[i] = *(const frag_t*)&As[((wm + 16*i + fr) * 8 + csw) * 8];
                #pragma unroll
                for (int j = 0; j < 4; ++j)
                    b[j] = *(const frag_t*)&Bs[((wn + 16*j + fr) * 8 + csw) * 8];
                #pragma unroll
                for (int i = 0; i < 2; ++i)
                    #pragma unroll
                    for (int j = 0; j < 4; ++j)
                        acc_in[i][j] = __builtin_amdgcn_mfma_f32_16x16x32_bf16(
                                           a[i], b[j], acc_in[i][j], 0, 0, 0);
            }
        }
        #pragma unroll
        for (int i = 0; i < 2; ++i)
            #pragma unroll
            for (int r = 0; r < 4; ++r) {
                const int gm = m0 + wm + 16*i + q*4 + r;
                const float w = W[(size_t)gm * 64 + nidx];
                #pragma unroll
                for (int j = 0; j < 4; ++j) acc_out[i][j][r] += w * acc_in[i][j][r];
            }
    }
    #pragma unroll
    for (int i = 0; i < 2; ++i)
        #pragma unroll
        for (int j = 0; j < 4; ++j)
            #pragma unroll
            for (int r = 0; r < 4; ++r) {
                const int gm = m0 + wm + 16*i + q*4 + r;
                const int gn = n0 + wn + 16*j + fr;
                if constexpr (ATOMIC) atomicAdd(&C[(size_t)gm * ldC + gn], acc_out[i][j][r]);
                else C[(size_t)gm * ldC + gn] = acc_out[i][j][r];
            }
}

extern "C" void kernel_launch(void* const* d_in, const int* in_sizes, int n_in,
                              void* d_out, int out_size, void* d_ws, size_t ws_size,
                              hipStream_t stream) {
    const float* x  = (const float*)d_in[0];   // [8192, 1024]
    const float* w1 = (const float*)d_in[1];   // [8192, 64]
    const float* w2 = (const float*)d_in[2];   // [8192, 64]
    const float* F  = (const float*)d_in[3];   // [64, 1024, 128]
    const float* Rk = (const float*)d_in[4];   // [64, 128, 1024] = (8192, 1024)
    float* out = (float*)d_out;                // [8192, 1024]

    char* ws = (char*)d_ws;
    const size_t MB = (size_t)1 << 20;

    if (ws_size >= 160 * MB) {
        // ---- main path: pure-GEMM pipeline, 160 MiB footprint ----
        ushort_t* y    = (ushort_t*)ws;               // [0,128) MiB: y, then g in place
        ushort_t* x_bf = (ushort_t*)(ws + 128 * MB);  // [128,144)
        ushort_t* F_t2 = (ushort_t*)(ws + 144 * MB);  // [144,160): F_t2[n*128+r, d]
        ushort_t* Rk_t = x_bf;                        // overlays x_bf after GEMM1

        convert_bf<<<4096, 256, 0, stream>>>(x, x_bf, 1048576);
        // per-n transpose: F[n] (1024x128) -> F_t2[n*128 .. n*128+128) x 1024
        transpose_bf<<<dim3(16, 2, 64), 256, 0, stream>>>(
            F, F_t2, 1024, 128, 131072, 131072);

        // GEMM1: y = x_bf @ F_t2^T (M=8192, N=8192, K=1024), bf16 out,
        // 256^2 8-phase counted-vmcnt kernel.
        kc_gemm256<true><<<dim3(32, 32), 512, 0, stream>>>(
            x_bf, F_t2, y, 1024, 1024, 8192, 16);

        // mid: h = w1-reduce(y); y <- g = w2 (x) h   (in place)
        mid_fuse<<<2048, 256, 0, stream>>>(y, w1, w2);

        // Rk_t[d, n*128+r] (1024 x 8192), overlays x_bf (dead)
        transpose_bf<<<dim3(128, 16, 1), 256, 0, stream>>>(
            Rk, Rk_t, 8192, 1024, 0, 0);

        // GEMM2: out = g @ Rk_t^T (M=8192, N=1024, K=8192), fp32 out.
        // N=1024 -> only 128 blocks at 256^2 (half the CUs idle), so keep
        // the 128^2 kernel here; split-K 256^2 is the next candidate.
        kc_gemm<false><<<dim3(64, 8), 256, 0, stream>>>(
            y, Rk_t, out, 8192, 8192, 1024, 128);
    } else {
        // ---- fallback: round-3 fold pipeline, 38 MiB footprint ----
        float*    h    = (float*)ws;
        ushort_t* x_bf = (ushort_t*)(ws + 4  * MB);
        ushort_t* Rk_t = (ushort_t*)(ws + 4  * MB);   // overlays x_bf after stage 1
        ushort_t* F_t  = (ushort_t*)(ws + 20 * MB);   // F_t[128, 65536]
        ushort_t* h_bf = (ushort_t*)(ws + 36 * MB);

        hipMemsetAsync(h, 0, 4 * MB, stream);
        convert_bf<<<4096, 256, 0, stream>>>(x, x_bf, 1048576);
        transpose_bf<<<dim3(1024, 2, 1), 256, 0, stream>>>(F, F_t, 65536, 128, 0, 0);

        kc_gemm_fold<10, 16, true><<<dim3(128, 1, 8), 256, 0, stream>>>(
            x_bf, w1, F_t, h, 1024, 65536, 128, 128);

        convert_bf<<<512, 256, 0, stream>>>(h, h_bf, 131072);
        transpose_bf<<<dim3(128, 16, 1), 256, 0, stream>>>(Rk, Rk_t, 8192, 1024, 0, 0);

        kc_gemm_fold<7, 2, false><<<dim3(128, 8, 1), 256, 0, stream>>>(
            h_bf, w2, Rk_t, out, 128, 8192, 1024, 128);
    }
}

// Round 3
// 481.291 us; speedup vs baseline: 1.0721x; 1.0721x over previous
//
#include <hip/hip_runtime.h>
#include <stdint.h>

// ---------------------------------------------------------------------------
// KnowledgeCircuit: B=4 S=2048 D=1024 N=64 R=128, M = B*S = 8192 tokens.
// Round 8 = Round 7 resubmit (bench infra failed twice; no counter data).
// GEMM1 256x256 8-phase with OPERAND REGISTER RESIDENCY.
// Round-6 lesson: quadrant phases that re-read both operands do 48 KB of
// ds_read per wave per K-tile (2x the minimum) -> LDS-pipe-bound, MfmaUtil
// 27.7%. Fix: a_ regs live across 2 phases, b0_/b1_ live across the tile;
// per-phase ds_read_b128 count = 12/4/8/0 (24 total = minimum).
//   GEMM1: y[m, n*128+r] = sum_d x[m,d] F[n,d,r]   (kc_gemm256, bf16 out)
//   mid  : h[m,r] = sum_n w1[m,n] y[m,n*128+r];  y <- g[m,nr] = w2[m,n]h[m,r]
//   GEMM2: out = g @ Rk_flat                       (kc_gemm 128^2, fp32 out)
// Ledger (verified): per K-tile T,
//   reads: p1 ds-reads A-ih0,B-jh0(buf); p2 reads B-jh1; p3 reads A-ih1.
//   issues: p1 -> T+1 second halves (4 loads, buf^1; those regions last
//           ds-read at T-1.p2/p3, >=1 barrier ago);
//           p3 -> T+2 A-first (2 loads, buf; region last read T.p1);
//           p4 -> T+2 B-first (2 loads, buf; region last read T.p1).
//   vmcnt(4) at p4-end leaves T.p3+T.p4's 4 loads in flight and clears all
//   of tile T+1 -> every ds-read target resident at read time. Last two
//   tiles vmcnt(0). Raw s_barrier (never __syncthreads -> no vmcnt(0) drain).
// ---------------------------------------------------------------------------

typedef unsigned short ushort_t;
typedef __attribute__((ext_vector_type(8))) short frag_t;   // 8 bf16
typedef __attribute__((ext_vector_type(4))) float f32x4;

#define BK 64

__device__ __forceinline__ unsigned short f2bf(float f) {
    unsigned int u = __builtin_bit_cast(unsigned int, f);
    u = (u + 0x7FFFu + ((u >> 16) & 1u)) >> 16;   // RTNE
    return (unsigned short)u;
}
__device__ __forceinline__ float bf2f_lo(unsigned int v) {
    return __builtin_bit_cast(float, v << 16);
}
__device__ __forceinline__ float bf2f_hi(unsigned int v) {
    return __builtin_bit_cast(float, v & 0xFFFF0000u);
}

__device__ __forceinline__ void glds16(const ushort_t* g, ushort_t* l) {
    __builtin_amdgcn_global_load_lds(
        (const __attribute__((address_space(1))) unsigned int*)g,
        (__attribute__((address_space(3))) unsigned int*)l,
        16, 0, 0);
}

// ---------------- prepass: fp32 -> bf16 elementwise -------------------------
__global__ __launch_bounds__(256) void convert_bf(const float* __restrict__ in,
                                                  ushort_t* __restrict__ out, int n8) {
    int idx = blockIdx.x * 256 + threadIdx.x;
    if (idx >= n8) return;
    const float4 v0 = ((const float4*)in)[idx * 2];
    const float4 v1 = ((const float4*)in)[idx * 2 + 1];
    unsigned short b[8] = { f2bf(v0.x), f2bf(v0.y), f2bf(v0.z), f2bf(v0.w),
                            f2bf(v1.x), f2bf(v1.y), f2bf(v1.z), f2bf(v1.w) };
    ((uint4*)out)[idx] = *(const uint4*)b;
}

// ---------------- prepass: fp32 RxC -> bf16 CxR transpose (batched) ---------
__global__ __launch_bounds__(256) void transpose_bf(const float* __restrict__ in,
                                                    ushort_t* __restrict__ out,
                                                    int R, int C,
                                                    long in_bstride, long out_bstride) {
    __shared__ float tile[64][65];
    in  += (long)blockIdx.z * in_bstride;
    out += (long)blockIdx.z * out_bstride;
    const int t  = threadIdx.x;
    const int r0 = blockIdx.x * 64;
    const int c0 = blockIdx.y * 64;
    const int ci = t & 63;
    const int rb = t >> 6;
    #pragma unroll
    for (int p = 0; p < 16; ++p)
        tile[rb + 4 * p][ci] = in[(size_t)(r0 + rb + 4 * p) * C + c0 + ci];
    __syncthreads();
    const int cw = t >> 2;
    const int rg = (t & 3) * 16;
    unsigned short buf[16];
    #pragma unroll
    for (int k = 0; k < 16; ++k)
        buf[k] = f2bf(tile[rg + k][cw]);
    uint4* dst = (uint4*)&out[(size_t)(c0 + cw) * R + r0 + rg];
    dst[0] = *(const uint4*)&buf[0];
    dst[1] = *(const uint4*)&buf[8];
}

// ---------------- mid: h = w1-reduce(y); y <- g = w2 (x) h (in place) -------
__global__ __launch_bounds__(256) void mid_fuse(ushort_t* __restrict__ y,
                                                const float* __restrict__ w1,
                                                const float* __restrict__ w2) {
    const int m    = blockIdx.x * 4 + (threadIdx.x >> 6);
    const int lane = threadIdx.x & 63;
    unsigned int* yrow = (unsigned int*)(y + (size_t)m * 8192);
    const float* w1r = w1 + (size_t)m * 64;
    const float* w2r = w2 + (size_t)m * 64;
    float h0 = 0.f, h1 = 0.f;
    #pragma unroll 16
    for (int n = 0; n < 64; ++n) {
        const unsigned int v = yrow[n * 64 + lane];
        const float w = w1r[n];
        h0 += w * bf2f_lo(v);
        h1 += w * bf2f_hi(v);
    }
    #pragma unroll 16
    for (int n = 0; n < 64; ++n) {
        const float w = w2r[n];
        yrow[n * 64 + lane] =
            (unsigned int)f2bf(w * h0) | ((unsigned int)f2bf(w * h1) << 16);
    }
}

// ---------------- 256x256 8-phase GEMM (T2+T3+T4+T5, reg-resident ops) ------
// C[m,n] = sum_k Ab[m,k] * Bt[n,k]; 512 threads, 8 waves (2M x 4N),
// per-wave 128x64 output, BK=64, 128 KiB LDS double buffer.
template<bool OUT_BF16>
__global__ __launch_bounds__(512, 2)
void kc_gemm256(const ushort_t* __restrict__ Ab, const ushort_t* __restrict__ Bt,
                void* __restrict__ Cout, int ldA, int ldB, int ldC, int ksteps)
{
    __shared__ ushort_t As[2][256 * BK];   // 2 x 32 KiB
    __shared__ ushort_t Bs[2][256 * BK];   // 2 x 32 KiB

    const int t    = threadIdx.x;
    const int lane = t & 63;
    const int wv   = t >> 6;
    const int m0   = blockIdx.x * 256;
    const int n0   = blockIdx.y * 256;

    const int wm = (wv >> 2) * 128;    // wave M-half: rows [wm, wm+128)
    const int wn = (wv & 3) * 64;      // wave N-quarter: cols [wn, wn+64)
    const int fr = lane & 15;
    const int q  = lane >> 4;
    const int e  = fr & 7;
    const int lrow = lane >> 3;        // staging: row within 8-row wave chunk
    const int lchk = lane & 7;         // staging: 16B chunk within row

    f32x4 acc[8][4];
    #pragma unroll
    for (int i = 0; i < 8; ++i)
        #pragma unroll
        for (int j = 0; j < 4; ++j)
            acc[i][j] = (f32x4){0.f, 0.f, 0.f, 0.f};

    // operand residency: a_ spans 2 phases (one ih-half), b0_/b1_ span the tile
    frag_t a_[2][4], b0_[2][2], b1_[2][2];

// One load batch = 512 threads x 16B = 64 rows. Source k-chunk is
// XOR-pre-swizzled (chunk ^ (row&7)) so linear LDS holds swizzled data;
// ds_read applies the same involution -> conflict-free (measured 0).
#define ISSUE_A(abuf, ih, piece, kt) do {                                     \
        const int r0_ = (piece) * 128 + (ih) * 64 + wv * 8;                   \
        const int rr_ = r0_ + lrow;                                           \
        glds16(Ab + (size_t)(m0 + rr_) * ldA + (kt) + ((lchk ^ (rr_ & 7)) << 3), \
               &As[abuf][r0_ * BK]);                                          \
    } while (0)
#define ISSUE_B(bbuf, jh, piece, kt) do {                                     \
        const int r0_ = (piece) * 128 + (jh) * 32 + wv * 8 + (wv >> 2) * 32;  \
        const int rr_ = r0_ + lrow;                                           \
        glds16(Bt + (size_t)(n0 + rr_) * ldB + (kt) + ((lchk ^ (rr_ & 7)) << 3), \
               &Bs[bbuf][r0_ * BK]);                                          \
    } while (0)
#define BAR() do { __builtin_amdgcn_s_barrier();                              \
                   __builtin_amdgcn_sched_barrier(0); } while (0)
#define VMCNT(n) do { asm volatile("s_waitcnt vmcnt(" #n ")" ::: "memory");   \
                      __builtin_amdgcn_sched_barrier(0); } while (0)
// ds-load one A-half (8 x ds_read_b128) into a_
#define LOAD_A(pbuf, ih) do {                                                 \
        _Pragma("unroll")                                                     \
        for (int kk = 0; kk < 2; ++kk) {                                      \
            const int cs_ = ((kk * 4 + q) ^ e) * 8;                           \
            _Pragma("unroll")                                                 \
            for (int ii = 0; ii < 4; ++ii)                                    \
                a_[kk][ii] = *(const frag_t*)&As[pbuf][                       \
                    (wm + ((ih) * 4 + ii) * 16 + fr) * BK + cs_];             \
        }                                                                     \
    } while (0)
// ds-load one B-half (4 x ds_read_b128) into breg
#define LOAD_B(pbuf, jh, breg) do {                                           \
        _Pragma("unroll")                                                     \
        for (int kk = 0; kk < 2; ++kk) {                                      \
            const int cs_ = ((kk * 4 + q) ^ e) * 8;                           \
            _Pragma("unroll")                                                 \
            for (int jj = 0; jj < 2; ++jj)                                    \
                breg[kk][jj] = *(const frag_t*)&Bs[pbuf][                     \
                    (wn + ((jh) * 2 + jj) * 16 + fr) * BK + cs_];             \
        }                                                                     \
    } while (0)
// one C-quadrant: 16 MFMA from registers only
#define MFMA_Q(ih, jh, breg) do {                                             \
        __builtin_amdgcn_s_setprio(1);                                        \
        _Pragma("unroll")                                                     \
        for (int kk = 0; kk < 2; ++kk)                                        \
            _Pragma("unroll")                                                 \
            for (int ii = 0; ii < 4; ++ii)                                    \
                _Pragma("unroll")                                             \
                for (int jj = 0; jj < 2; ++jj)                                \
                    acc[(ih) * 4 + ii][(jh) * 2 + jj] =                       \
                        __builtin_amdgcn_mfma_f32_16x16x32_bf16(              \
                            a_[kk][ii], breg[kk][jj],                         \
                            acc[(ih) * 4 + ii][(jh) * 2 + jj], 0, 0, 0);      \
        __builtin_amdgcn_s_setprio(0);                                        \
    } while (0)

    // prologue: all of tile 0 (8 loads) + tile 1 FIRST halves (4 loads).
    // vmcnt(4) -> tile 0 resident; tile1 first halves may stay in flight
    // (exactly the steady-state invariant at a p1 entry).
    ISSUE_A(0, 0, 0, 0); ISSUE_A(0, 0, 1, 0);
    ISSUE_A(0, 1, 0, 0); ISSUE_A(0, 1, 1, 0);
    ISSUE_B(0, 0, 0, 0); ISSUE_B(0, 0, 1, 0);
    ISSUE_B(0, 1, 0, 0); ISSUE_B(0, 1, 1, 0);
    if (ksteps > 1) {
        ISSUE_A(1, 0, 0, BK); ISSUE_A(1, 0, 1, BK);
        ISSUE_B(1, 0, 0, BK); ISSUE_B(1, 0, 1, BK);
        VMCNT(4);
    } else {
        VMCNT(0);
    }
    BAR();

    for (int T = 0; T < ksteps; ++T) {
        const int buf = T & 1;
        const int kn1 = (T + 1) * BK;
        const int kn2 = (T + 2) * BK;
        // p1: issue T+1 second halves into buf^1 (regions last ds-read at
        //     T-1.p2/p3, >=1 barrier ago). ds-load a0,b0; MFMA Q(0,0).
        if (T + 1 < ksteps) {
            ISSUE_A(buf ^ 1, 1, 0, kn1); ISSUE_A(buf ^ 1, 1, 1, kn1);
            ISSUE_B(buf ^ 1, 1, 0, kn1); ISSUE_B(buf ^ 1, 1, 1, kn1);
        }
        LOAD_A(buf, 0);
        LOAD_B(buf, 0, b0_);
        MFMA_Q(0, 0, b0_);
        BAR();
        // p2: ds-load b1 only (a0 stays in regs); MFMA Q(0,1).
        LOAD_B(buf, 1, b1_);
        MFMA_Q(0, 1, b1_);
        BAR();
        // p3: A-ih0(buf) free (last read T.p1) -> issue T+2 A-first.
        //     ds-load a1 (overwrites a_); MFMA Q(1,0) with resident b0.
        if (T + 2 < ksteps) { ISSUE_A(buf, 0, 0, kn2); ISSUE_A(buf, 0, 1, kn2); }
        LOAD_A(buf, 1);
        MFMA_Q(1, 0, b0_);
        BAR();
        // p4: B-jh0(buf) free -> issue T+2 B-first. Pure-MFMA phase (zero
        //     ds_reads): MFMA Q(1,1) from registers, then the counted wait.
        if (T + 2 < ksteps) { ISSUE_B(buf, 0, 0, kn2); ISSUE_B(buf, 0, 1, kn2); }
        MFMA_Q(1, 1, b1_);
        // counted wait: keep p3+p4's 4 loads in flight; clears tile T+1.
        if (T < ksteps - 2) { VMCNT(4); } else { VMCNT(0); }
        BAR();
    }

    // epilogue: C/D layout col=lane&15, row=q*4+reg
    #pragma unroll
    for (int i = 0; i < 8; ++i) {
        #pragma unroll
        for (int r = 0; r < 4; ++r) {
            const int gm = m0 + wm + 16 * i + q * 4 + r;
            #pragma unroll
            for (int j = 0; j < 4; ++j) {
                const int gn = n0 + wn + 16 * j + fr;
                if constexpr (OUT_BF16)
                    ((ushort_t*)Cout)[(size_t)gm * ldC + gn] = f2bf(acc[i][j][r]);
                else
                    ((float*)Cout)[(size_t)gm * ldC + gn] = acc[i][j][r];
            }
        }
    }
#undef ISSUE_A
#undef ISSUE_B
#undef BAR
#undef VMCNT
#undef LOAD_A
#undef LOAD_B
#undef MFMA_Q
}

// ---------------- pure GEMM (128x128, round-5 known-good) -------------------
template<bool OUT_BF16>
__global__ __launch_bounds__(256, 3)
void kc_gemm(const ushort_t* __restrict__ Ab, const ushort_t* __restrict__ Bt,
             void* __restrict__ Cout, int ldA, int ldB, int ldC, int ksteps)
{
    __shared__ ushort_t As[128 * BK];
    __shared__ ushort_t Bs[128 * BK];

    const int t    = threadIdx.x;
    const int lane = t & 63;
    const int wv   = t >> 6;
    const int m0   = blockIdx.x * 128;
    const int n0   = blockIdx.y * 128;

    const int wm = (wv & 1) * 64;
    const int wn = (wv >> 1) * 64;
    const int fr = lane & 15;
    const int q  = lane >> 4;
    const int e  = fr & 7;

    int srow[4], scol[4];
    #pragma unroll
    for (int c = 0; c < 4; ++c) {
        const int s = (wv * 4 + c) * 64 + lane;
        srow[c] = s >> 3;
        scol[c] = ((s & 7) ^ (srow[c] & 7)) * 8;
    }

    f32x4 acc[4][4];
    #pragma unroll
    for (int i = 0; i < 4; ++i)
        #pragma unroll
        for (int j = 0; j < 4; ++j)
            acc[i][j] = (f32x4){0.f, 0.f, 0.f, 0.f};

    for (int ss = 0; ss < ksteps; ++ss) {
        const int k0 = ss * BK;

        __syncthreads();
        #pragma unroll
        for (int c = 0; c < 4; ++c)
            glds16(Ab + (size_t)(m0 + srow[c]) * ldA + k0 + scol[c],
                   &As[(wv * 4 + c) * 512]);
        #pragma unroll
        for (int c = 0; c < 4; ++c)
            glds16(Bt + (size_t)(n0 + srow[c]) * ldB + k0 + scol[c],
                   &Bs[(wv * 4 + c) * 512]);
        __syncthreads();

        #pragma unroll
        for (int kk = 0; kk < 2; ++kk) {
            const int csw = (kk * 4 + q) ^ e;
            frag_t a[4], b[4];
            #pragma unroll
            for (int i = 0; i < 4; ++i)
                a[i] = *(const frag_t*)&As[((wm + 16 * i + fr) * 8 + csw) * 8];
            #pragma unroll
            for (int j = 0; j < 4; ++j)
                b[j] = *(const frag_t*)&Bs[((wn + 16 * j + fr) * 8 + csw) * 8];
            #pragma unroll
            for (int i = 0; i < 4; ++i)
                #pragma unroll
                for (int j = 0; j < 4; ++j)
                    acc[i][j] = __builtin_amdgcn_mfma_f32_16x16x32_bf16(
                                    a[i], b[j], acc[i][j], 0, 0, 0);
        }
    }

    #pragma unroll
    for (int i = 0; i < 4; ++i) {
        #pragma unroll
        for (int r = 0; r < 4; ++r) {
            const int gm = m0 + wm + 16 * i + q * 4 + r;
            #pragma unroll
            for (int j = 0; j < 4; ++j) {
                const int gn = n0 + wn + 16 * j + fr;
                if constexpr (OUT_BF16)
                    ((ushort_t*)Cout)[(size_t)gm * ldC + gn] = f2bf(acc[i][j][r]);
                else
                    ((float*)Cout)[(size_t)gm * ldC + gn] = acc[i][j][r];
            }
        }
    }
}

// ---------------- fallback fold-GEMM (round-3, known-good) ------------------
template<int SHIFT, int SEG_STEPS, bool ATOMIC>
__global__ __launch_bounds__(256, 4)
void kc_gemm_fold(const ushort_t* __restrict__ Ab, const float* __restrict__ W,
                  const ushort_t* __restrict__ Bt, float* __restrict__ C,
                  int ldA, int ldB, int ldC, int ksteps)
{
    __shared__ ushort_t As[64 * BK];
    __shared__ ushort_t Bs[128 * BK];
    const int t = threadIdx.x, lane = t & 63, wv = t >> 6;
    const int m0 = blockIdx.x * 64, n0 = blockIdx.y * 128;
    const int kbase = blockIdx.z * ksteps * BK;
    const int wm = (wv & 1) * 32, wn = (wv >> 1) * 64;
    const int fr = lane & 15, q = lane >> 4, e = fr & 7;
    int arow[2], acol[2], brow[4], bcol[4];
    #pragma unroll
    for (int c = 0; c < 2; ++c) {
        const int s = (wv * 2 + c) * 64 + lane;
        arow[c] = s >> 3; acol[c] = ((s & 7) ^ (arow[c] & 7)) * 8;
    }
    #pragma unroll
    for (int c = 0; c < 4; ++c) {
        const int s = (wv * 4 + c) * 64 + lane;
        brow[c] = s >> 3; bcol[c] = ((s & 7) ^ (brow[c] & 7)) * 8;
    }
    f32x4 acc_out[2][4];
    #pragma unroll
    for (int i = 0; i < 2; ++i)
        #pragma unroll
        for (int j = 0; j < 4; ++j) acc_out[i][j] = (f32x4){0.f,0.f,0.f,0.f};
    const int nsegs = ksteps / SEG_STEPS;
    for (int seg = 0; seg < nsegs; ++seg) {
        const int segk = kbase + seg * SEG_STEPS * BK;
        const int nidx = segk >> SHIFT;
        f32x4 acc_in[2][4];
        #pragma unroll
        for (int i = 0; i < 2; ++i)
            #pragma unroll
            for (int j = 0; j < 4; ++j) acc_in[i][j] = (f32x4){0.f,0.f,0.f,0.f};
        for (int ss = 0; ss < SEG_STEPS; ++ss) {
            const int k0 = segk + ss * BK;
            const int d0 = k0 & ((1 << SHIFT) - 1);
            __syncthreads();
            #pragma unroll
            for (int c = 0; c < 2; ++c)
                glds16(Ab + (size_t)(m0 + arow[c]) * ldA + d0 + acol[c],
                       &As[(wv * 2 + c) * 512]);
            #pragma unroll
            for (int c = 0; c < 4; ++c)
                glds16(Bt + (size_t)(n0 + brow[c]) * ldB + k0 + bcol[c],
                       &Bs[(wv * 4 + c) * 512]);
            __syncthreads();
            #pragma unroll
            for (int kk = 0; kk < 2; ++kk) {
                const int csw = (kk * 4 + q) ^ e;
                frag_t a[2], b[4];
                #pragma unroll
                for (int i = 0; i < 2; ++i)
                    a[i] = *(const frag_t*)&As[((wm + 16*i + fr) * 8 + csw) * 8];
                #pragma unroll
                for (int j = 0; j < 4; ++j)
                    b[j] = *(const frag_t*)&Bs[((wn + 16*j + fr) * 8 + csw) * 8];
                #pragma unroll
                for (int i = 0; i < 2; ++i)
                    #pragma unroll
                    for (int j = 0; j < 4; ++j)
                        acc_in[i][j] = __builtin_amdgcn_mfma_f32_16x16x32_bf16(
                                           a[i], b[j], acc_in[i][j], 0, 0, 0);
            }
        }
        #pragma unroll
        for (int i = 0; i < 2; ++i)
            #pragma unroll
            for (int r = 0; r < 4; ++r) {
                const int gm = m0 + wm + 16*i + q*4 + r;
                const float w = W[(size_t)gm * 64 + nidx];
                #pragma unroll
                for (int j = 0; j < 4; ++j) acc_out[i][j][r] += w * acc_in[i][j][r];
            }
    }
    #pragma unroll
    for (int i = 0; i < 2; ++i)
        #pragma unroll
        for (int j = 0; j < 4; ++j)
            #pragma unroll
            for (int r = 0; r < 4; ++r) {
                const int gm = m0 + wm + 16*i + q*4 + r;
                const int gn = n0 + wn + 16*j + fr;
                if constexpr (ATOMIC) atomicAdd(&C[(size_t)gm * ldC + gn], acc_out[i][j][r]);
                else C[(size_t)gm * ldC + gn] = acc_out[i][j][r];
            }
}

extern "C" void kernel_launch(void* const* d_in, const int* in_sizes, int n_in,
                              void* d_out, int out_size, void* d_ws, size_t ws_size,
                              hipStream_t stream) {
    const float* x  = (const float*)d_in[0];   // [8192, 1024]
    const float* w1 = (const float*)d_in[1];   // [8192, 64]
    const float* w2 = (const float*)d_in[2];   // [8192, 64]
    const float* F  = (const float*)d_in[3];   // [64, 1024, 128]
    const float* Rk = (const float*)d_in[4];   // [64, 128, 1024] = (8192, 1024)
    float* out = (float*)d_out;                // [8192, 1024]

    char* ws = (char*)d_ws;
    const size_t MB = (size_t)1 << 20;

    if (ws_size >= 160 * MB) {
        // ---- main path: pure-GEMM pipeline, 160 MiB footprint ----
        ushort_t* y    = (ushort_t*)ws;               // [0,128) MiB: y, then g in place
        ushort_t* x_bf = (ushort_t*)(ws + 128 * MB);  // [128,144)
        ushort_t* F_t2 = (ushort_t*)(ws + 144 * MB);  // [144,160): F_t2[n*128+r, d]
        ushort_t* Rk_t = x_bf;                        // overlays x_bf after GEMM1

        convert_bf<<<4096, 256, 0, stream>>>(x, x_bf, 1048576);
        // per-n transpose: F[n] (1024x128) -> F_t2[n*128 .. n*128+128) x 1024
        transpose_bf<<<dim3(16, 2, 64), 256, 0, stream>>>(
            F, F_t2, 1024, 128, 131072, 131072);

        // GEMM1: y = x_bf @ F_t2^T (M=8192, N=8192, K=1024), bf16 out,
        // 256^2 8-phase counted-vmcnt kernel with reg-resident operands.
        kc_gemm256<true><<<dim3(32, 32), 512, 0, stream>>>(
            x_bf, F_t2, y, 1024, 1024, 8192, 16);

        // mid: h = w1-reduce(y); y <- g = w2 (x) h   (in place)
        mid_fuse<<<2048, 256, 0, stream>>>(y, w1, w2);

        // Rk_t[d, n*128+r] (1024 x 8192), overlays x_bf (dead)
        transpose_bf<<<dim3(128, 16, 1), 256, 0, stream>>>(
            Rk, Rk_t, 8192, 1024, 0, 0);

        // GEMM2: out = g @ Rk_t^T (M=8192, N=1024, K=8192), fp32 out.
        // N=1024 -> only 128 blocks at 256^2 (half the CUs idle), so keep
        // the 128^2 kernel here; split-K 256^2 is the next candidate.
        kc_gemm<false><<<dim3(64, 8), 256, 0, stream>>>(
            y, Rk_t, out, 8192, 8192, 1024, 128);
    } else {
        // ---- fallback: round-3 fold pipeline, 38 MiB footprint ----
        float*    h    = (float*)ws;
        ushort_t* x_bf = (ushort_t*)(ws + 4  * MB);
        ushort_t* Rk_t = (ushort_t*)(ws + 4  * MB);   // overlays x_bf after stage 1
        ushort_t* F_t  = (ushort_t*)(ws + 20 * MB);   // F_t[128, 65536]
        ushort_t* h_bf = (ushort_t*)(ws + 36 * MB);

        hipMemsetAsync(h, 0, 4 * MB, stream);
        convert_bf<<<4096, 256, 0, stream>>>(x, x_bf, 1048576);
        transpose_bf<<<dim3(1024, 2, 1), 256, 0, stream>>>(F, F_t, 65536, 128, 0, 0);

        kc_gemm_fold<10, 16, true><<<dim3(128, 1, 8), 256, 0, stream>>>(
            x_bf, w1, F_t, h, 1024, 65536, 128, 128);

        convert_bf<<<512, 256, 0, stream>>>(h, h_bf, 131072);
        transpose_bf<<<dim3(128, 16, 1), 256, 0, stream>>>(Rk, Rk_t, 8192, 1024, 0, 0);

        kc_gemm_fold<7, 2, false><<<dim3(128, 8, 1), 256, 0, stream>>>(
            h_bf, w2, Rk_t, out, 128, 8192, 1024, 128);
    }
}

// Round 4
// 477.046 us; speedup vs baseline: 1.0816x; 1.0089x over previous
//
#include <hip/hip_runtime.h>
#include <stdint.h>

// ---------------------------------------------------------------------------
// KnowledgeCircuit: B=4 S=2048 D=1024 N=64 R=128, M = B*S = 8192 tokens.
// Round 9: GEMM1 256x256 8-phase with ISSUE-AHEAD ds_reads (m201 ordering).
// Round-8 lesson: with BAR -> ds_read -> MFMA per phase, the ds_read
// issue+latency sits inside every barrier-to-barrier critical path
// (6560 cyc/K-tile vs 2484 MFMA floor, MfmaUtil 33%). Fix: issue each
// phase's ds_reads at the END of the previous phase (after its MFMA),
// so phases become BAR -> MFMA(data already landed) -> pre-issue next.
// Operand reg ping-pong: aA (p1/p2) loaded at prev p4-tail; b1_ at p1-tail;
// aB (p3/p4) at p2-tail; b0_ at p4-tail.
//   GEMM1: y[m, n*128+r] = sum_d x[m,d] F[n,d,r]   (kc_gemm256, bf16 out)
//   mid  : h[m,r] = sum_n w1[m,n] y[m,n*128+r];  y <- g[m,nr] = w2[m,n]h[m,r]
//   GEMM2: out = g @ Rk_flat                       (kc_gemm 128^2, fp32 out)
// G-load ledger (FIFO, re-verified): issues p1: T+1 2nd halves (4, buf^1);
// p2: T+2 A-first (2, buf); p3: T+2 B-first (2, buf). At T.p4's vmcnt(4):
// outstanding [T-1.p2 x2, T-1.p3 x2, T.p1 x4, T.p2 x2, T.p3 x2] -> oldest 8
// complete -> tile T+1 fully resident; 4 remain (T+2 first halves).
// Every pre-issued ds_read target resident; every G-write's region
// last-read >=1 barrier earlier. Last two tiles vmcnt(0).
// Raw s_barrier only (no __syncthreads -> no vmcnt(0) drain).
// ---------------------------------------------------------------------------

typedef unsigned short ushort_t;
typedef __attribute__((ext_vector_type(8))) short frag_t;   // 8 bf16
typedef __attribute__((ext_vector_type(4))) float f32x4;

#define BK 64

__device__ __forceinline__ unsigned short f2bf(float f) {
    unsigned int u = __builtin_bit_cast(unsigned int, f);
    u = (u + 0x7FFFu + ((u >> 16) & 1u)) >> 16;   // RTNE
    return (unsigned short)u;
}
__device__ __forceinline__ float bf2f_lo(unsigned int v) {
    return __builtin_bit_cast(float, v << 16);
}
__device__ __forceinline__ float bf2f_hi(unsigned int v) {
    return __builtin_bit_cast(float, v & 0xFFFF0000u);
}

__device__ __forceinline__ void glds16(const ushort_t* g, ushort_t* l) {
    __builtin_amdgcn_global_load_lds(
        (const __attribute__((address_space(1))) unsigned int*)g,
        (__attribute__((address_space(3))) unsigned int*)l,
        16, 0, 0);
}

// ---------------- prepass: fp32 -> bf16 elementwise -------------------------
__global__ __launch_bounds__(256) void convert_bf(const float* __restrict__ in,
                                                  ushort_t* __restrict__ out, int n8) {
    int idx = blockIdx.x * 256 + threadIdx.x;
    if (idx >= n8) return;
    const float4 v0 = ((const float4*)in)[idx * 2];
    const float4 v1 = ((const float4*)in)[idx * 2 + 1];
    unsigned short b[8] = { f2bf(v0.x), f2bf(v0.y), f2bf(v0.z), f2bf(v0.w),
                            f2bf(v1.x), f2bf(v1.y), f2bf(v1.z), f2bf(v1.w) };
    ((uint4*)out)[idx] = *(const uint4*)b;
}

// ---------------- prepass: fp32 RxC -> bf16 CxR transpose (batched) ---------
__global__ __launch_bounds__(256) void transpose_bf(const float* __restrict__ in,
                                                    ushort_t* __restrict__ out,
                                                    int R, int C,
                                                    long in_bstride, long out_bstride) {
    __shared__ float tile[64][65];
    in  += (long)blockIdx.z * in_bstride;
    out += (long)blockIdx.z * out_bstride;
    const int t  = threadIdx.x;
    const int r0 = blockIdx.x * 64;
    const int c0 = blockIdx.y * 64;
    const int ci = t & 63;
    const int rb = t >> 6;
    #pragma unroll
    for (int p = 0; p < 16; ++p)
        tile[rb + 4 * p][ci] = in[(size_t)(r0 + rb + 4 * p) * C + c0 + ci];
    __syncthreads();
    const int cw = t >> 2;
    const int rg = (t & 3) * 16;
    unsigned short buf[16];
    #pragma unroll
    for (int k = 0; k < 16; ++k)
        buf[k] = f2bf(tile[rg + k][cw]);
    uint4* dst = (uint4*)&out[(size_t)(c0 + cw) * R + r0 + rg];
    dst[0] = *(const uint4*)&buf[0];
    dst[1] = *(const uint4*)&buf[8];
}

// ---------------- mid: h = w1-reduce(y); y <- g = w2 (x) h (in place) -------
__global__ __launch_bounds__(256) void mid_fuse(ushort_t* __restrict__ y,
                                                const float* __restrict__ w1,
                                                const float* __restrict__ w2) {
    const int m    = blockIdx.x * 4 + (threadIdx.x >> 6);
    const int lane = threadIdx.x & 63;
    unsigned int* yrow = (unsigned int*)(y + (size_t)m * 8192);
    const float* w1r = w1 + (size_t)m * 64;
    const float* w2r = w2 + (size_t)m * 64;
    float h0 = 0.f, h1 = 0.f;
    #pragma unroll 16
    for (int n = 0; n < 64; ++n) {
        const unsigned int v = yrow[n * 64 + lane];
        const float w = w1r[n];
        h0 += w * bf2f_lo(v);
        h1 += w * bf2f_hi(v);
    }
    #pragma unroll 16
    for (int n = 0; n < 64; ++n) {
        const float w = w2r[n];
        yrow[n * 64 + lane] =
            (unsigned int)f2bf(w * h0) | ((unsigned int)f2bf(w * h1) << 16);
    }
}

// ---------------- 256x256 8-phase GEMM (issue-ahead, T2+T3+T4+T5) -----------
// C[m,n] = sum_k Ab[m,k] * Bt[n,k]; 512 threads, 8 waves (2M x 4N),
// per-wave 128x64 output, BK=64, 128 KiB LDS double buffer.
template<bool OUT_BF16>
__global__ __launch_bounds__(512, 2)
void kc_gemm256(const ushort_t* __restrict__ Ab, const ushort_t* __restrict__ Bt,
                void* __restrict__ Cout, int ldA, int ldB, int ldC, int ksteps)
{
    __shared__ ushort_t As[2][256 * BK];   // 2 x 32 KiB
    __shared__ ushort_t Bs[2][256 * BK];   // 2 x 32 KiB

    const int t    = threadIdx.x;
    const int lane = t & 63;
    const int wv   = t >> 6;
    const int m0   = blockIdx.x * 256;
    const int n0   = blockIdx.y * 256;

    const int wm = (wv >> 2) * 128;    // wave M-half: rows [wm, wm+128)
    const int wn = (wv & 3) * 64;      // wave N-quarter: cols [wn, wn+64)
    const int fr = lane & 15;
    const int q  = lane >> 4;
    const int e  = fr & 7;
    const int lrow = lane >> 3;        // staging: row within 8-row wave chunk
    const int lchk = lane & 7;         // staging: 16B chunk within row

    f32x4 acc[8][4];
    #pragma unroll
    for (int i = 0; i < 8; ++i)
        #pragma unroll
        for (int j = 0; j < 4; ++j)
            acc[i][j] = (f32x4){0.f, 0.f, 0.f, 0.f};

    // operand ping-pong: aA = A-half for p1/p2 (loaded prev p4-tail),
    // aB = A-half for p3/p4 (loaded p2-tail); b0_ p1&p3; b1_ p2&p4.
    frag_t aA[2][4], aB[2][4], b0_[2][2], b1_[2][2];

// One load batch = 512 threads x 16B = 64 rows. Source k-chunk is
// XOR-pre-swizzled (chunk ^ (row&7)) so linear LDS holds swizzled data;
// ds_read applies the same involution -> conflict-free (measured 0).
#define ISSUE_A(abuf, ih, piece, kt) do {                                     \
        const int r0_ = (piece) * 128 + (ih) * 64 + wv * 8;                   \
        const int rr_ = r0_ + lrow;                                           \
        glds16(Ab + (size_t)(m0 + rr_) * ldA + (kt) + ((lchk ^ (rr_ & 7)) << 3), \
               &As[abuf][r0_ * BK]);                                          \
    } while (0)
#define ISSUE_B(bbuf, jh, piece, kt) do {                                     \
        const int r0_ = (piece) * 128 + (jh) * 32 + wv * 8 + (wv >> 2) * 32;  \
        const int rr_ = r0_ + lrow;                                           \
        glds16(Bt + (size_t)(n0 + rr_) * ldB + (kt) + ((lchk ^ (rr_ & 7)) << 3), \
               &Bs[bbuf][r0_ * BK]);                                          \
    } while (0)
#define BAR() do { __builtin_amdgcn_s_barrier();                              \
                   __builtin_amdgcn_sched_barrier(0); } while (0)
#define VMCNT(n) do { asm volatile("s_waitcnt vmcnt(" #n ")" ::: "memory");   \
                      __builtin_amdgcn_sched_barrier(0); } while (0)
// ds-load one A-half (8 x ds_read_b128) into areg (plain loads: compiler
// inserts fine-grained lgkmcnt before the consuming MFMAs)
#define LOAD_A(pbuf, ih, areg) do {                                           \
        _Pragma("unroll")                                                     \
        for (int kk = 0; kk < 2; ++kk) {                                      \
            const int cs_ = ((kk * 4 + q) ^ e) * 8;                           \
            _Pragma("unroll")                                                 \
            for (int ii = 0; ii < 4; ++ii)                                    \
                areg[kk][ii] = *(const frag_t*)&As[pbuf][                     \
                    (wm + ((ih) * 4 + ii) * 16 + fr) * BK + cs_];             \
        }                                                                     \
    } while (0)
// ds-load one B-half (4 x ds_read_b128) into breg
#define LOAD_B(pbuf, jh, breg) do {                                           \
        _Pragma("unroll")                                                     \
        for (int kk = 0; kk < 2; ++kk) {                                      \
            const int cs_ = ((kk * 4 + q) ^ e) * 8;                           \
            _Pragma("unroll")                                                 \
            for (int jj = 0; jj < 2; ++jj)                                    \
                breg[kk][jj] = *(const frag_t*)&Bs[pbuf][                     \
                    (wn + ((jh) * 2 + jj) * 16 + fr) * BK + cs_];             \
        }                                                                     \
    } while (0)
// one C-quadrant: 16 MFMA from registers only
#define MFMA_Q(ih, jh, areg, breg) do {                                       \
        __builtin_amdgcn_s_setprio(1);                                        \
        _Pragma("unroll")                                                     \
        for (int kk = 0; kk < 2; ++kk)                                        \
            _Pragma("unroll")                                                 \
            for (int ii = 0; ii < 4; ++ii)                                    \
                _Pragma("unroll")                                             \
                for (int jj = 0; jj < 2; ++jj)                                \
                    acc[(ih) * 4 + ii][(jh) * 2 + jj] =                       \
                        __builtin_amdgcn_mfma_f32_16x16x32_bf16(              \
                            areg[kk][ii], breg[kk][jj],                       \
                            acc[(ih) * 4 + ii][(jh) * 2 + jj], 0, 0, 0);      \
        __builtin_amdgcn_s_setprio(0);                                        \
    } while (0)

    // prologue: all of tile 0 (8 loads) + tile 1 FIRST halves (4 loads,
    // matching the steady-state queue [A-first x2, B-first x2]).
    ISSUE_A(0, 0, 0, 0); ISSUE_A(0, 0, 1, 0);
    ISSUE_A(0, 1, 0, 0); ISSUE_A(0, 1, 1, 0);
    ISSUE_B(0, 0, 0, 0); ISSUE_B(0, 0, 1, 0);
    ISSUE_B(0, 1, 0, 0); ISSUE_B(0, 1, 1, 0);
    if (ksteps > 1) {
        ISSUE_A(1, 0, 0, BK); ISSUE_A(1, 0, 1, BK);
        ISSUE_B(1, 0, 0, BK); ISSUE_B(1, 0, 1, BK);
        VMCNT(4);
    } else {
        VMCNT(0);
    }
    BAR();
    // pre-issue for T0.p1 (tile-0 first halves resident per vmcnt above)
    LOAD_A(0, 0, aA);
    LOAD_B(0, 0, b0_);

    for (int T = 0; T < ksteps; ++T) {
        const int buf = T & 1;
        const int kn1 = (T + 1) * BK;
        const int kn2 = (T + 2) * BK;
        // p1: MFMA Q(0,0) on pre-issued aA,b0. G-issue T+1 second halves
        //     (buf^1; regions last ds-read at T-1.p1/p2 tails, >=2 bars ago).
        //     Tail: pre-issue b1 (B-jh1(buf), resident since T-1.p4 vmcnt).
        BAR();
        if (T + 1 < ksteps) {
            ISSUE_A(buf ^ 1, 1, 0, kn1); ISSUE_A(buf ^ 1, 1, 1, kn1);
            ISSUE_B(buf ^ 1, 1, 0, kn1); ISSUE_B(buf ^ 1, 1, 1, kn1);
        }
        MFMA_Q(0, 0, aA, b0_);
        LOAD_B(buf, 1, b1_);
        // p2: MFMA Q(0,1). G-issue T+2 A-first (A-ih0(buf) last read at
        //     T-1.p4-tail, >=1 bar). Tail: pre-issue aB (A-ih1(buf)).
        BAR();
        if (T + 2 < ksteps) { ISSUE_A(buf, 0, 0, kn2); ISSUE_A(buf, 0, 1, kn2); }
        MFMA_Q(0, 1, aA, b1_);
        LOAD_A(buf, 1, aB);
        // p3: MFMA Q(1,0). G-issue T+2 B-first (B-jh0(buf) last read at
        //     T-1.p4-tail). No tail reads.
        BAR();
        if (T + 2 < ksteps) { ISSUE_B(buf, 0, 0, kn2); ISSUE_B(buf, 0, 1, kn2); }
        MFMA_Q(1, 0, aB, b0_);
        // p4: pure-MFMA phase, then the counted wait; tail pre-issues
        //     T+1.p1's operands from buf^1 (first halves resident per vmcnt).
        BAR();
        MFMA_Q(1, 1, aB, b1_);
        if (T < ksteps - 2) { VMCNT(4); } else { VMCNT(0); }
        BAR();
        if (T + 1 < ksteps) {
            LOAD_A(buf ^ 1, 0, aA);
            LOAD_B(buf ^ 1, 0, b0_);
        }
    }

    // epilogue: C/D layout col=lane&15, row=q*4+reg
    #pragma unroll
    for (int i = 0; i < 8; ++i) {
        #pragma unroll
        for (int r = 0; r < 4; ++r) {
            const int gm = m0 + wm + 16 * i + q * 4 + r;
            #pragma unroll
            for (int j = 0; j < 4; ++j) {
                const int gn = n0 + wn + 16 * j + fr;
                if constexpr (OUT_BF16)
                    ((ushort_t*)Cout)[(size_t)gm * ldC + gn] = f2bf(acc[i][j][r]);
                else
                    ((float*)Cout)[(size_t)gm * ldC + gn] = acc[i][j][r];
            }
        }
    }
#undef ISSUE_A
#undef ISSUE_B
#undef BAR
#undef VMCNT
#undef LOAD_A
#undef LOAD_B
#undef MFMA_Q
}

// ---------------- pure GEMM (128x128, round-5 known-good) -------------------
template<bool OUT_BF16>
__global__ __launch_bounds__(256, 3)
void kc_gemm(const ushort_t* __restrict__ Ab, const ushort_t* __restrict__ Bt,
             void* __restrict__ Cout, int ldA, int ldB, int ldC, int ksteps)
{
    __shared__ ushort_t As[128 * BK];
    __shared__ ushort_t Bs[128 * BK];

    const int t    = threadIdx.x;
    const int lane = t & 63;
    const int wv   = t >> 6;
    const int m0   = blockIdx.x * 128;
    const int n0   = blockIdx.y * 128;

    const int wm = (wv & 1) * 64;
    const int wn = (wv >> 1) * 64;
    const int fr = lane & 15;
    const int q  = lane >> 4;
    const int e  = fr & 7;

    int srow[4], scol[4];
    #pragma unroll
    for (int c = 0; c < 4; ++c) {
        const int s = (wv * 4 + c) * 64 + lane;
        srow[c] = s >> 3;
        scol[c] = ((s & 7) ^ (srow[c] & 7)) * 8;
    }

    f32x4 acc[4][4];
    #pragma unroll
    for (int i = 0; i < 4; ++i)
        #pragma unroll
        for (int j = 0; j < 4; ++j)
            acc[i][j] = (f32x4){0.f, 0.f, 0.f, 0.f};

    for (int ss = 0; ss < ksteps; ++ss) {
        const int k0 = ss * BK;

        __syncthreads();
        #pragma unroll
        for (int c = 0; c < 4; ++c)
            glds16(Ab + (size_t)(m0 + srow[c]) * ldA + k0 + scol[c],
                   &As[(wv * 4 + c) * 512]);
        #pragma unroll
        for (int c = 0; c < 4; ++c)
            glds16(Bt + (size_t)(n0 + srow[c]) * ldB + k0 + scol[c],
                   &Bs[(wv * 4 + c) * 512]);
        __syncthreads();

        #pragma unroll
        for (int kk = 0; kk < 2; ++kk) {
            const int csw = (kk * 4 + q) ^ e;
            frag_t a[4], b[4];
            #pragma unroll
            for (int i = 0; i < 4; ++i)
                a[i] = *(const frag_t*)&As[((wm + 16 * i + fr) * 8 + csw) * 8];
            #pragma unroll
            for (int j = 0; j < 4; ++j)
                b[j] = *(const frag_t*)&Bs[((wn + 16 * j + fr) * 8 + csw) * 8];
            #pragma unroll
            for (int i = 0; i < 4; ++i)
                #pragma unroll
                for (int j = 0; j < 4; ++j)
                    acc[i][j] = __builtin_amdgcn_mfma_f32_16x16x32_bf16(
                                    a[i], b[j], acc[i][j], 0, 0, 0);
        }
    }

    #pragma unroll
    for (int i = 0; i < 4; ++i) {
        #pragma unroll
        for (int r = 0; r < 4; ++r) {
            const int gm = m0 + wm + 16 * i + q * 4 + r;
            #pragma unroll
            for (int j = 0; j < 4; ++j) {
                const int gn = n0 + wn + 16 * j + fr;
                if constexpr (OUT_BF16)
                    ((ushort_t*)Cout)[(size_t)gm * ldC + gn] = f2bf(acc[i][j][r]);
                else
                    ((float*)Cout)[(size_t)gm * ldC + gn] = acc[i][j][r];
            }
        }
    }
}

// ---------------- fallback fold-GEMM (round-3, known-good) ------------------
template<int SHIFT, int SEG_STEPS, bool ATOMIC>
__global__ __launch_bounds__(256, 4)
void kc_gemm_fold(const ushort_t* __restrict__ Ab, const float* __restrict__ W,
                  const ushort_t* __restrict__ Bt, float* __restrict__ C,
                  int ldA, int ldB, int ldC, int ksteps)
{
    __shared__ ushort_t As[64 * BK];
    __shared__ ushort_t Bs[128 * BK];
    const int t = threadIdx.x, lane = t & 63, wv = t >> 6;
    const int m0 = blockIdx.x * 64, n0 = blockIdx.y * 128;
    const int kbase = blockIdx.z * ksteps * BK;
    const int wm = (wv & 1) * 32, wn = (wv >> 1) * 64;
    const int fr = lane & 15, q = lane >> 4, e = fr & 7;
    int arow[2], acol[2], brow[4], bcol[4];
    #pragma unroll
    for (int c = 0; c < 2; ++c) {
        const int s = (wv * 2 + c) * 64 + lane;
        arow[c] = s >> 3; acol[c] = ((s & 7) ^ (arow[c] & 7)) * 8;
    }
    #pragma unroll
    for (int c = 0; c < 4; ++c) {
        const int s = (wv * 4 + c) * 64 + lane;
        brow[c] = s >> 3; bcol[c] = ((s & 7) ^ (brow[c] & 7)) * 8;
    }
    f32x4 acc_out[2][4];
    #pragma unroll
    for (int i = 0; i < 2; ++i)
        #pragma unroll
        for (int j = 0; j < 4; ++j) acc_out[i][j] = (f32x4){0.f,0.f,0.f,0.f};
    const int nsegs = ksteps / SEG_STEPS;
    for (int seg = 0; seg < nsegs; ++seg) {
        const int segk = kbase + seg * SEG_STEPS * BK;
        const int nidx = segk >> SHIFT;
        f32x4 acc_in[2][4];
        #pragma unroll
        for (int i = 0; i < 2; ++i)
            #pragma unroll
            for (int j = 0; j < 4; ++j) acc_in[i][j] = (f32x4){0.f,0.f,0.f,0.f};
        for (int ss = 0; ss < SEG_STEPS; ++ss) {
            const int k0 = segk + ss * BK;
            const int d0 = k0 & ((1 << SHIFT) - 1);
            __syncthreads();
            #pragma unroll
            for (int c = 0; c < 2; ++c)
                glds16(Ab + (size_t)(m0 + arow[c]) * ldA + d0 + acol[c],
                       &As[(wv * 2 + c) * 512]);
            #pragma unroll
            for (int c = 0; c < 4; ++c)
                glds16(Bt + (size_t)(n0 + brow[c]) * ldB + k0 + bcol[c],
                       &Bs[(wv * 4 + c) * 512]);
            __syncthreads();
            #pragma unroll
            for (int kk = 0; kk < 2; ++kk) {
                const int csw = (kk * 4 + q) ^ e;
                frag_t a[2], b[4];
                #pragma unroll
                for (int i = 0; i < 2; ++i)
                    a[i] = *(const frag_t*)&As[((wm + 16*i + fr) * 8 + csw) * 8];
                #pragma unroll
                for (int j = 0; j < 4; ++j)
                    b[j] = *(const frag_t*)&Bs[((wn + 16*j + fr) * 8 + csw) * 8];
                #pragma unroll
                for (int i = 0; i < 2; ++i)
                    #pragma unroll
                    for (int j = 0; j < 4; ++j)
                        acc_in[i][j] = __builtin_amdgcn_mfma_f32_16x16x32_bf16(
                                           a[i], b[j], acc_in[i][j], 0, 0, 0);
            }
        }
        #pragma unroll
        for (int i = 0; i < 2; ++i)
            #pragma unroll
            for (int r = 0; r < 4; ++r) {
                const int gm = m0 + wm + 16*i + q*4 + r;
                const float w = W[(size_t)gm * 64 + nidx];
                #pragma unroll
                for (int j = 0; j < 4; ++j) acc_out[i][j][r] += w * acc_in[i][j][r];
            }
    }
    #pragma unroll
    for (int i = 0; i < 2; ++i)
        #pragma unroll
        for (int j = 0; j < 4; ++j)
            #pragma unroll
            for (int r = 0; r < 4; ++r) {
                const int gm = m0 + wm + 16*i + q*4 + r;
                const int gn = n0 + wn + 16*j + fr;
                if constexpr (ATOMIC) atomicAdd(&C[(size_t)gm * ldC + gn], acc_out[i][j][r]);
                else C[(size_t)gm * ldC + gn] = acc_out[i][j][r];
            }
}

extern "C" void kernel_launch(void* const* d_in, const int* in_sizes, int n_in,
                              void* d_out, int out_size, void* d_ws, size_t ws_size,
                              hipStream_t stream) {
    const float* x  = (const float*)d_in[0];   // [8192, 1024]
    const float* w1 = (const float*)d_in[1];   // [8192, 64]
    const float* w2 = (const float*)d_in[2];   // [8192, 64]
    const float* F  = (const float*)d_in[3];   // [64, 1024, 128]
    const float* Rk = (const float*)d_in[4];   // [64, 128, 1024] = (8192, 1024)
    float* out = (float*)d_out;                // [8192, 1024]

    char* ws = (char*)d_ws;
    const size_t MB = (size_t)1 << 20;

    if (ws_size >= 160 * MB) {
        // ---- main path: pure-GEMM pipeline, 160 MiB footprint ----
        ushort_t* y    = (ushort_t*)ws;               // [0,128) MiB: y, then g in place
        ushort_t* x_bf = (ushort_t*)(ws + 128 * MB);  // [128,144)
        ushort_t* F_t2 = (ushort_t*)(ws + 144 * MB);  // [144,160): F_t2[n*128+r, d]
        ushort_t* Rk_t = x_bf;                        // overlays x_bf after GEMM1

        convert_bf<<<4096, 256, 0, stream>>>(x, x_bf, 1048576);
        // per-n transpose: F[n] (1024x128) -> F_t2[n*128 .. n*128+128) x 1024
        transpose_bf<<<dim3(16, 2, 64), 256, 0, stream>>>(
            F, F_t2, 1024, 128, 131072, 131072);

        // GEMM1: y = x_bf @ F_t2^T (M=8192, N=8192, K=1024), bf16 out,
        // 256^2 issue-ahead 8-phase counted-vmcnt kernel.
        kc_gemm256<true><<<dim3(32, 32), 512, 0, stream>>>(
            x_bf, F_t2, y, 1024, 1024, 8192, 16);

        // mid: h = w1-reduce(y); y <- g = w2 (x) h   (in place)
        mid_fuse<<<2048, 256, 0, stream>>>(y, w1, w2);

        // Rk_t[d, n*128+r] (1024 x 8192), overlays x_bf (dead)
        transpose_bf<<<dim3(128, 16, 1), 256, 0, stream>>>(
            Rk, Rk_t, 8192, 1024, 0, 0);

        // GEMM2: out = g @ Rk_t^T (M=8192, N=1024, K=8192), fp32 out.
        // N=1024 -> only 128 blocks at 256^2 (half the CUs idle), so keep
        // the 128^2 kernel here; split-K 256^2 is the next candidate.
        kc_gemm<false><<<dim3(64, 8), 256, 0, stream>>>(
            y, Rk_t, out, 8192, 8192, 1024, 128);
    } else {
        // ---- fallback: round-3 fold pipeline, 38 MiB footprint ----
        float*    h    = (float*)ws;
        ushort_t* x_bf = (ushort_t*)(ws + 4  * MB);
        ushort_t* Rk_t = (ushort_t*)(ws + 4  * MB);   // overlays x_bf after stage 1
        ushort_t* F_t  = (ushort_t*)(ws + 20 * MB);   // F_t[128, 65536]
        ushort_t* h_bf = (ushort_t*)(ws + 36 * MB);

        hipMemsetAsync(h, 0, 4 * MB, stream);
        convert_bf<<<4096, 256, 0, stream>>>(x, x_bf, 1048576);
        transpose_bf<<<dim3(1024, 2, 1), 256, 0, stream>>>(F, F_t, 65536, 128, 0, 0);

        kc_gemm_fold<10, 16, true><<<dim3(128, 1, 8), 256, 0, stream>>>(
            x_bf, w1, F_t, h, 1024, 65536, 128, 128);

        convert_bf<<<512, 256, 0, stream>>>(h, h_bf, 131072);
        transpose_bf<<<dim3(128, 16, 1), 256, 0, stream>>>(Rk, Rk_t, 8192, 1024, 0, 0);

        kc_gemm_fold<7, 2, false><<<dim3(128, 8, 1), 256, 0, stream>>>(
            h_bf, w2, Rk_t, out, 128, 8192, 1024, 128);
    }
}

// Round 5
// 454.297 us; speedup vs baseline: 1.1358x; 1.0501x over previous
//
#include <hip/hip_runtime.h>
#include <stdint.h>

// ---------------------------------------------------------------------------
// KnowledgeCircuit: B=4 S=2048 D=1024 N=64 R=128, M = B*S = 8192 tokens.
// Round 10: CONSOLIDATION. Three 256^2 8-phase ports (r6: 203us, r8: 175us,
// r9: 169us + scratch spill) all lost to the plain 128^2 2-phase kernel
// (144.7us, MfmaUtil 42%). Revert GEMM1 to 128^2 and fix the real non-GEMM
// cost instead: mid_fuse was 4B/lane (u32) on 256 MiB of traffic -> ~2x
// below BW ceiling (guideline 13). mid_fuse_v uses 16B/lane uint4 both
// directions + __shfl_xor(16/32) reduce across the 4 n-classes.
//   GEMM1: y[m, n*128+r] = sum_d x[m,d] F[n,d,r]   (kc_gemm 128^2, bf16 out)
//   mid  : h[m,r] = sum_n w1[m,n] y[m,n*128+r];  y <- g[m,nr] = w2[m,n]h[m,r]
//   GEMM2: out = g @ Rk_flat                       (kc_gemm 128^2, fp32 out)
// Core GEMM: 128x128 block, 2x2 waves, 64x64 wave tile, BK=64,
// global_load_lds, XOR-swizzled LDS (0 conflicts measured).
// ---------------------------------------------------------------------------

typedef unsigned short ushort_t;
typedef __attribute__((ext_vector_type(8))) short frag_t;   // 8 bf16
typedef __attribute__((ext_vector_type(4))) float f32x4;

#define BK 64

__device__ __forceinline__ unsigned short f2bf(float f) {
    unsigned int u = __builtin_bit_cast(unsigned int, f);
    u = (u + 0x7FFFu + ((u >> 16) & 1u)) >> 16;   // RTNE
    return (unsigned short)u;
}
__device__ __forceinline__ float bf2f_lo(unsigned int v) {
    return __builtin_bit_cast(float, v << 16);
}
__device__ __forceinline__ float bf2f_hi(unsigned int v) {
    return __builtin_bit_cast(float, v & 0xFFFF0000u);
}

__device__ __forceinline__ void glds16(const ushort_t* g, ushort_t* l) {
    __builtin_amdgcn_global_load_lds(
        (const __attribute__((address_space(1))) unsigned int*)g,
        (__attribute__((address_space(3))) unsigned int*)l,
        16, 0, 0);
}

// ---------------- prepass: fp32 -> bf16 elementwise -------------------------
__global__ __launch_bounds__(256) void convert_bf(const float* __restrict__ in,
                                                  ushort_t* __restrict__ out, int n8) {
    int idx = blockIdx.x * 256 + threadIdx.x;
    if (idx >= n8) return;
    const float4 v0 = ((const float4*)in)[idx * 2];
    const float4 v1 = ((const float4*)in)[idx * 2 + 1];
    unsigned short b[8] = { f2bf(v0.x), f2bf(v0.y), f2bf(v0.z), f2bf(v0.w),
                            f2bf(v1.x), f2bf(v1.y), f2bf(v1.z), f2bf(v1.w) };
    ((uint4*)out)[idx] = *(const uint4*)b;
}

// ---------------- prepass: fp32 RxC -> bf16 CxR transpose (batched) ---------
__global__ __launch_bounds__(256) void transpose_bf(const float* __restrict__ in,
                                                    ushort_t* __restrict__ out,
                                                    int R, int C,
                                                    long in_bstride, long out_bstride) {
    __shared__ float tile[64][65];
    in  += (long)blockIdx.z * in_bstride;
    out += (long)blockIdx.z * out_bstride;
    const int t  = threadIdx.x;
    const int r0 = blockIdx.x * 64;
    const int c0 = blockIdx.y * 64;
    const int ci = t & 63;
    const int rb = t >> 6;
    #pragma unroll
    for (int p = 0; p < 16; ++p)
        tile[rb + 4 * p][ci] = in[(size_t)(r0 + rb + 4 * p) * C + c0 + ci];
    __syncthreads();
    const int cw = t >> 2;
    const int rg = (t & 3) * 16;
    unsigned short buf[16];
    #pragma unroll
    for (int k = 0; k < 16; ++k)
        buf[k] = f2bf(tile[rg + k][cw]);
    uint4* dst = (uint4*)&out[(size_t)(c0 + cw) * R + r0 + rg];
    dst[0] = *(const uint4*)&buf[0];
    dst[1] = *(const uint4*)&buf[8];
}

// ---------------- mid (vectorized): h = w1-reduce(y); y <- g = w2 (x) h -----
// One wave per token row. Lane l: n-class ng = l>>4 (n = 4i+ng, i=0..15),
// rp-quad rp4 = l&15 (u32 cols rp4*4..rp4*4+3 within each n-segment).
// Wave reads/writes 4 KiB contiguous per i -> 16B/lane fully coalesced.
// h partials combined across the 4 n-classes via shfl_xor 16/32.
__global__ __launch_bounds__(256) void mid_fuse_v(ushort_t* __restrict__ y,
                                                  const float* __restrict__ w1,
                                                  const float* __restrict__ w2) {
    const int m    = blockIdx.x * 4 + (threadIdx.x >> 6);
    const int lane = threadIdx.x & 63;
    uint4* yrow = (uint4*)(y + (size_t)m * 8192);   // 1024 uint4 per row
    const float* w1r = w1 + (size_t)m * 64;
    const float* w2r = w2 + (size_t)m * 64;
    const int ng  = lane >> 4;
    const int rp4 = lane & 15;

    float h[8];
    #pragma unroll
    for (int k = 0; k < 8; ++k) h[k] = 0.f;

    #pragma unroll
    for (int i = 0; i < 16; ++i) {
        const int n = i * 4 + ng;
        const uint4 v = yrow[n * 16 + rp4];        // u32 idx n*64 + rp4*4
        const float w = w1r[n];
        h[0] += w * bf2f_lo(v.x); h[1] += w * bf2f_hi(v.x);
        h[2] += w * bf2f_lo(v.y); h[3] += w * bf2f_hi(v.y);
        h[4] += w * bf2f_lo(v.z); h[5] += w * bf2f_hi(v.z);
        h[6] += w * bf2f_lo(v.w); h[7] += w * bf2f_hi(v.w);
    }
    #pragma unroll
    for (int k = 0; k < 8; ++k) {
        h[k] += __shfl_xor(h[k], 16, 64);
        h[k] += __shfl_xor(h[k], 32, 64);
    }
    // g[m, n*128+r] = w2[m,n] * h[m,r], written in place (same coords as read)
    #pragma unroll
    for (int i = 0; i < 16; ++i) {
        const int n = i * 4 + ng;
        const float w = w2r[n];
        uint4 o;
        o.x = (unsigned)f2bf(w * h[0]) | ((unsigned)f2bf(w * h[1]) << 16);
        o.y = (unsigned)f2bf(w * h[2]) | ((unsigned)f2bf(w * h[3]) << 16);
        o.z = (unsigned)f2bf(w * h[4]) | ((unsigned)f2bf(w * h[5]) << 16);
        o.w = (unsigned)f2bf(w * h[6]) | ((unsigned)f2bf(w * h[7]) << 16);
        yrow[n * 16 + rp4] = o;
    }
}

// ---------------- pure GEMM (128x128, round-5 known-good) -------------------
// C[m,n] = sum_k Ab[m,k] * Bt[n,k]; 128x128 block, 2x2 waves, 64x64/wave.
template<bool OUT_BF16>
__global__ __launch_bounds__(256, 3)
void kc_gemm(const ushort_t* __restrict__ Ab, const ushort_t* __restrict__ Bt,
             void* __restrict__ Cout, int ldA, int ldB, int ldC, int ksteps)
{
    __shared__ ushort_t As[128 * BK];   // 16 KB: 8 chunks(16B)/row, XOR-swizzled
    __shared__ ushort_t Bs[128 * BK];   // 16 KB

    const int t    = threadIdx.x;
    const int lane = t & 63;
    const int wv   = t >> 6;
    const int m0   = blockIdx.x * 128;
    const int n0   = blockIdx.y * 128;

    const int wm = (wv & 1) * 64;
    const int wn = (wv >> 1) * 64;
    const int fr = lane & 15;
    const int q  = lane >> 4;
    const int e  = fr & 7;

    int srow[4], scol[4];
    #pragma unroll
    for (int c = 0; c < 4; ++c) {
        const int s = (wv * 4 + c) * 64 + lane;
        srow[c] = s >> 3;
        scol[c] = ((s & 7) ^ (srow[c] & 7)) * 8;   // XOR swizzle in global k
    }

    f32x4 acc[4][4];
    #pragma unroll
    for (int i = 0; i < 4; ++i)
        #pragma unroll
        for (int j = 0; j < 4; ++j)
            acc[i][j] = (f32x4){0.f, 0.f, 0.f, 0.f};

    for (int ss = 0; ss < ksteps; ++ss) {
        const int k0 = ss * BK;

        __syncthreads();
        #pragma unroll
        for (int c = 0; c < 4; ++c)
            glds16(Ab + (size_t)(m0 + srow[c]) * ldA + k0 + scol[c],
                   &As[(wv * 4 + c) * 512]);
        #pragma unroll
        for (int c = 0; c < 4; ++c)
            glds16(Bt + (size_t)(n0 + srow[c]) * ldB + k0 + scol[c],
                   &Bs[(wv * 4 + c) * 512]);
        __syncthreads();

        #pragma unroll
        for (int kk = 0; kk < 2; ++kk) {
            const int csw = (kk * 4 + q) ^ e;
            frag_t a[4], b[4];
            #pragma unroll
            for (int i = 0; i < 4; ++i)
                a[i] = *(const frag_t*)&As[((wm + 16 * i + fr) * 8 + csw) * 8];
            #pragma unroll
            for (int j = 0; j < 4; ++j)
                b[j] = *(const frag_t*)&Bs[((wn + 16 * j + fr) * 8 + csw) * 8];
            #pragma unroll
            for (int i = 0; i < 4; ++i)
                #pragma unroll
                for (int j = 0; j < 4; ++j)
                    acc[i][j] = __builtin_amdgcn_mfma_f32_16x16x32_bf16(
                                    a[i], b[j], acc[i][j], 0, 0, 0);
        }
    }

    // epilogue: C/D layout col=lane&15, row=q*4+reg
    #pragma unroll
    for (int i = 0; i < 4; ++i) {
        #pragma unroll
        for (int r = 0; r < 4; ++r) {
            const int gm = m0 + wm + 16 * i + q * 4 + r;
            #pragma unroll
            for (int j = 0; j < 4; ++j) {
                const int gn = n0 + wn + 16 * j + fr;
                if constexpr (OUT_BF16)
                    ((ushort_t*)Cout)[(size_t)gm * ldC + gn] = f2bf(acc[i][j][r]);
                else
                    ((float*)Cout)[(size_t)gm * ldC + gn] = acc[i][j][r];
            }
        }
    }
}

// ---------------- fallback fold-GEMM (round-3, known-good) ------------------
template<int SHIFT, int SEG_STEPS, bool ATOMIC>
__global__ __launch_bounds__(256, 4)
void kc_gemm_fold(const ushort_t* __restrict__ Ab, const float* __restrict__ W,
                  const ushort_t* __restrict__ Bt, float* __restrict__ C,
                  int ldA, int ldB, int ldC, int ksteps)
{
    __shared__ ushort_t As[64 * BK];
    __shared__ ushort_t Bs[128 * BK];
    const int t = threadIdx.x, lane = t & 63, wv = t >> 6;
    const int m0 = blockIdx.x * 64, n0 = blockIdx.y * 128;
    const int kbase = blockIdx.z * ksteps * BK;
    const int wm = (wv & 1) * 32, wn = (wv >> 1) * 64;
    const int fr = lane & 15, q = lane >> 4, e = fr & 7;
    int arow[2], acol[2], brow[4], bcol[4];
    #pragma unroll
    for (int c = 0; c < 2; ++c) {
        const int s = (wv * 2 + c) * 64 + lane;
        arow[c] = s >> 3; acol[c] = ((s & 7) ^ (arow[c] & 7)) * 8;
    }
    #pragma unroll
    for (int c = 0; c < 4; ++c) {
        const int s = (wv * 4 + c) * 64 + lane;
        brow[c] = s >> 3; bcol[c] = ((s & 7) ^ (brow[c] & 7)) * 8;
    }
    f32x4 acc_out[2][4];
    #pragma unroll
    for (int i = 0; i < 2; ++i)
        #pragma unroll
        for (int j = 0; j < 4; ++j) acc_out[i][j] = (f32x4){0.f,0.f,0.f,0.f};
    const int nsegs = ksteps / SEG_STEPS;
    for (int seg = 0; seg < nsegs; ++seg) {
        const int segk = kbase + seg * SEG_STEPS * BK;
        const int nidx = segk >> SHIFT;
        f32x4 acc_in[2][4];
        #pragma unroll
        for (int i = 0; i < 2; ++i)
            #pragma unroll
            for (int j = 0; j < 4; ++j) acc_in[i][j] = (f32x4){0.f,0.f,0.f,0.f};
        for (int ss = 0; ss < SEG_STEPS; ++ss) {
            const int k0 = segk + ss * BK;
            const int d0 = k0 & ((1 << SHIFT) - 1);
            __syncthreads();
            #pragma unroll
            for (int c = 0; c < 2; ++c)
                glds16(Ab + (size_t)(m0 + arow[c]) * ldA + d0 + acol[c],
                       &As[(wv * 2 + c) * 512]);
            #pragma unroll
            for (int c = 0; c < 4; ++c)
                glds16(Bt + (size_t)(n0 + brow[c]) * ldB + k0 + bcol[c],
                       &Bs[(wv * 4 + c) * 512]);
            __syncthreads();
            #pragma unroll
            for (int kk = 0; kk < 2; ++kk) {
                const int csw = (kk * 4 + q) ^ e;
                frag_t a[2], b[4];
                #pragma unroll
                for (int i = 0; i < 2; ++i)
                    a[i] = *(const frag_t*)&As[((wm + 16*i + fr) * 8 + csw) * 8];
                #pragma unroll
                for (int j = 0; j < 4; ++j)
                    b[j] = *(const frag_t*)&Bs[((wn + 16*j + fr) * 8 + csw) * 8];
                #pragma unroll
                for (int i = 0; i < 2; ++i)
                    #pragma unroll
                    for (int j = 0; j < 4; ++j)
                        acc_in[i][j] = __builtin_amdgcn_mfma_f32_16x16x32_bf16(
                                           a[i], b[j], acc_in[i][j], 0, 0, 0);
            }
        }
        #pragma unroll
        for (int i = 0; i < 2; ++i)
            #pragma unroll
            for (int r = 0; r < 4; ++r) {
                const int gm = m0 + wm + 16*i + q*4 + r;
                const float w = W[(size_t)gm * 64 + nidx];
                #pragma unroll
                for (int j = 0; j < 4; ++j) acc_out[i][j][r] += w * acc_in[i][j][r];
            }
    }
    #pragma unroll
    for (int i = 0; i < 2; ++i)
        #pragma unroll
        for (int j = 0; j < 4; ++j)
            #pragma unroll
            for (int r = 0; r < 4; ++r) {
                const int gm = m0 + wm + 16*i + q*4 + r;
                const int gn = n0 + wn + 16*j + fr;
                if constexpr (ATOMIC) atomicAdd(&C[(size_t)gm * ldC + gn], acc_out[i][j][r]);
                else C[(size_t)gm * ldC + gn] = acc_out[i][j][r];
            }
}

extern "C" void kernel_launch(void* const* d_in, const int* in_sizes, int n_in,
                              void* d_out, int out_size, void* d_ws, size_t ws_size,
                              hipStream_t stream) {
    const float* x  = (const float*)d_in[0];   // [8192, 1024]
    const float* w1 = (const float*)d_in[1];   // [8192, 64]
    const float* w2 = (const float*)d_in[2];   // [8192, 64]
    const float* F  = (const float*)d_in[3];   // [64, 1024, 128]
    const float* Rk = (const float*)d_in[4];   // [64, 128, 1024] = (8192, 1024)
    float* out = (float*)d_out;                // [8192, 1024]

    char* ws = (char*)d_ws;
    const size_t MB = (size_t)1 << 20;

    if (ws_size >= 160 * MB) {
        // ---- main path: pure-GEMM pipeline, 160 MiB footprint ----
        ushort_t* y    = (ushort_t*)ws;               // [0,128) MiB: y, then g in place
        ushort_t* x_bf = (ushort_t*)(ws + 128 * MB);  // [128,144)
        ushort_t* F_t2 = (ushort_t*)(ws + 144 * MB);  // [144,160): F_t2[n*128+r, d]
        ushort_t* Rk_t = x_bf;                        // overlays x_bf after GEMM1

        convert_bf<<<4096, 256, 0, stream>>>(x, x_bf, 1048576);
        // per-n transpose: F[n] (1024x128) -> F_t2[n*128 .. n*128+128) x 1024
        transpose_bf<<<dim3(16, 2, 64), 256, 0, stream>>>(
            F, F_t2, 1024, 128, 131072, 131072);

        // GEMM1: y = x_bf @ F_t2^T   (M=8192, N=8192, K=1024), bf16 out
        kc_gemm<true><<<dim3(64, 64), 256, 0, stream>>>(
            x_bf, F_t2, y, 1024, 1024, 8192, 16);

        // mid: h = w1-reduce(y); y <- g = w2 (x) h   (in place, 16B/lane)
        mid_fuse_v<<<2048, 256, 0, stream>>>(y, w1, w2);

        // Rk_t[d, n*128+r] (1024 x 8192), overlays x_bf (dead)
        transpose_bf<<<dim3(128, 16, 1), 256, 0, stream>>>(
            Rk, Rk_t, 8192, 1024, 0, 0);

        // GEMM2: out = g @ Rk_t^T   (M=8192, N=1024, K=8192), fp32 out
        kc_gemm<false><<<dim3(64, 8), 256, 0, stream>>>(
            y, Rk_t, out, 8192, 8192, 1024, 128);
    } else {
        // ---- fallback: round-3 fold pipeline, 38 MiB footprint ----
        float*    h    = (float*)ws;
        ushort_t* x_bf = (ushort_t*)(ws + 4  * MB);
        ushort_t* Rk_t = (ushort_t*)(ws + 4  * MB);   // overlays x_bf after stage 1
        ushort_t* F_t  = (ushort_t*)(ws + 20 * MB);   // F_t[128, 65536]
        ushort_t* h_bf = (ushort_t*)(ws + 36 * MB);

        hipMemsetAsync(h, 0, 4 * MB, stream);
        convert_bf<<<4096, 256, 0, stream>>>(x, x_bf, 1048576);
        transpose_bf<<<dim3(1024, 2, 1), 256, 0, stream>>>(F, F_t, 65536, 128, 0, 0);

        kc_gemm_fold<10, 16, true><<<dim3(128, 1, 8), 256, 0, stream>>>(
            x_bf, w1, F_t, h, 1024, 65536, 128, 128);

        convert_bf<<<512, 256, 0, stream>>>(h, h_bf, 131072);
        transpose_bf<<<dim3(128, 16, 1), 256, 0, stream>>>(Rk, Rk_t, 8192, 1024, 0, 0);

        kc_gemm_fold<7, 2, false><<<dim3(128, 8, 1), 256, 0, stream>>>(
            h_bf, w2, Rk_t, out, 128, 8192, 1024, 128);
    }
}